// Round 6
// baseline (52.280 us; speedup 1.0000x reference)
//
#include <hip/hip_runtime.h>
#include <math.h>

// ---------------------------------------------------------------------------
// RISVQCLayer: angles = tanh(fused @ W^T + b) * pi  -> 4-qubit VQC -> (z+1)*pi
// B=65536, HID=256, R=16 runs (64 outputs/sample), fp32 in/out.
//
// R5: run-split waves for 4x occupancy. Block = 256 thr / 4 waves, one
// 16-sample tile per block; wave cg computes only acc[cg] (8 MFMAs) and owns
// runs 4cg..4cg+3 -> lane (l15,l4) owns ONE run (4 transcendental chains).
// Grid = 4096 blocks = 16384 waves (64/CU dispatched, was 4096 total).
// No barriers, no staging LDS (fused tile read per-wave, L1-shared within
// block); LDS = 9.2KB factor table with wave-private run slots (stride 9
// -> conflict-free). U-apply = one mfma_16x16x32_f16 per run with
// A=[U_hi|U_lo] split-fp16 (R4-verified), B=[se;se]. Z via shfl_xor(16,32).
// d_ws: [0,32K) Wf fp16 frags; [32K,48K) UA fp16 frags; [48K,64K) U fp32 tmp.
// ---------------------------------------------------------------------------

#define PI_F 3.14159265358979323846f

typedef _Float16 f16x4 __attribute__((ext_vector_type(4)));
typedef _Float16 f16x8 __attribute__((ext_vector_type(8)));
typedef float    f32x4 __attribute__((ext_vector_type(4)));

__device__ __forceinline__ void ry_gate(float st[16], float c, float s, int w) {
    const int m = 1 << (3 - w);
    #pragma unroll
    for (int i = 0; i < 16; ++i) {
        if (i & m) continue;
        float a = st[i];
        float b = st[i | m];
        st[i]     = c * a - s * b;
        st[i | m] = s * a + c * b;
    }
}

__device__ __forceinline__ void cnot_gate(float st[16], int cw, int tw) {
    const int cm = 1 << (3 - cw);
    const int tm = 1 << (3 - tw);
    #pragma unroll
    for (int i = 0; i < 16; ++i) {
        if ((i & cm) && !(i & tm)) {
            float tmp = st[i];
            st[i] = st[i | tm];
            st[i | tm] = tmp;
        }
    }
}

// prep: block0 -> U matrices then fp16 hi/lo A-fragments; block1 -> W frags.
// (layouts verified in R3/R4)
__global__ void prep_kernel(const float* __restrict__ vw,
                            const float* __restrict__ W,
                            char* __restrict__ ws) {
    const int tid = threadIdx.x;   // 256
    if (blockIdx.x == 0) {
        float* Ut = (float*)(ws + 49152);          // fp32 U[r][i][j]
        {   // phase 1: thread (r, j) computes column j of U_r
            const int r = tid >> 4, j = tid & 15;
            const float* wr = vw + r * 16;
            float cs[16], sn[16];
            #pragma unroll
            for (int i = 0; i < 16; ++i) {
                float h = wr[i] * 0.5f;
                cs[i] = __cosf(h);
                sn[i] = __sinf(h);
            }
            float st[16];
            #pragma unroll
            for (int i = 0; i < 16; ++i) st[i] = 0.f;
            st[j] = 1.f;
            #pragma unroll
            for (int w = 0; w < 4; ++w) ry_gate(st, cs[w], sn[w], w);
            cnot_gate(st, 0, 1);
            cnot_gate(st, 2, 3);
            #pragma unroll
            for (int w = 0; w < 4; ++w) ry_gate(st, cs[4 + w], sn[4 + w], w);
            cnot_gate(st, 1, 2);
            cnot_gate(st, 3, 0);
            #pragma unroll
            for (int w = 0; w < 4; ++w) ry_gate(st, cs[8 + w], sn[8 + w], w);
            cnot_gate(st, 0, 1);
            cnot_gate(st, 1, 2);
            cnot_gate(st, 2, 3);
            cnot_gate(st, 3, 0);
            #pragma unroll
            for (int w = 0; w < 4; ++w) ry_gate(st, cs[12 + w], sn[12 + w], w);
            #pragma unroll
            for (int i = 0; i < 16; ++i) Ut[r * 256 + i * 16 + j] = st[i];
        }
        __syncthreads();
        {   // phase 2: UA[r][lane]: k<16 -> hi(U[l15][k]), k>=16 -> lo(...)
            _Float16* UA = (_Float16*)(ws + 32768);
            #pragma unroll
            for (int t = 0; t < 4; ++t) {
                int f = t * 256 + tid;             // 0..1023
                int r = f >> 6, lane = f & 63;
                int l15 = lane & 15, l4 = lane >> 4;
                const float* urow = Ut + r * 256 + l15 * 16;
                f16x8 h;
                #pragma unroll
                for (int e = 0; e < 8; ++e) {
                    int kl = 8 * l4 + e;
                    if (kl < 16) {
                        h[e] = (_Float16)urow[kl];
                    } else {
                        float u = urow[kl - 16];
                        _Float16 hi = (_Float16)u;
                        h[e] = (_Float16)(u - (float)hi);
                    }
                }
                *(f16x8*)(UA + f * 8) = h;
            }
        }
    } else {
        // W fragments: row=cg*16+l15, k=(kk*4+l4)*8+e
        _Float16* Wh = (_Float16*)ws;
        #pragma unroll
        for (int t = 0; t < 8; ++t) {
            int f  = tid * 8 + t;            // fragment id 0..2047
            int cg = f >> 9;
            int kk = (f >> 6) & 7;
            int l  = f & 63;
            int row = cg * 16 + (l & 15);
            int k0  = (kk * 4 + (l >> 4)) * 8;
            const float* src = W + row * 256 + k0;
            f16x8 h;
            #pragma unroll
            for (int e = 0; e < 8; ++e) h[e] = (_Float16)src[e];
            *(f16x8*)(Wh + f * 8) = h;
        }
    }
}

__global__ __launch_bounds__(256, 6) void vqc_main_kernel(
        const float* __restrict__ fused,   // (65536, 256)
        const char* __restrict__ ws,       // Wf + UA fragments
        const float* __restrict__ bp,      // (64,)
        float* __restrict__ out) {         // (65536, 64)
    __shared__ float tab[16 * 16 * 9];     // [run][sample][a01[4],a23[4],pad]

    const int tid  = threadIdx.x;
    const int lane = tid & 63;
    const int cg   = tid >> 6;             // wave id = run group
    const int l15  = lane & 15;
    const int l4   = lane >> 4;
    const size_t s0 = (size_t)blockIdx.x * 16;
    const float* frow = fused + (s0 + l15) * 256;

    // ---- MFMA: acc[j] = pre[sample l15][angle 16cg+4l4+j] ----
    const f16x8* Wf = (const f16x8*)ws;
    f32x4 acc = {};
    #pragma unroll
    for (int kk = 0; kk < 8; ++kk) {
        float4 u0 = *(const float4*)(frow + kk * 32 + l4 * 8);
        float4 u1 = *(const float4*)(frow + kk * 32 + l4 * 8 + 4);
        f16x8 bf;
        bf[0] = (_Float16)u0.x; bf[1] = (_Float16)u0.y;
        bf[2] = (_Float16)u0.z; bf[3] = (_Float16)u0.w;
        bf[4] = (_Float16)u1.x; bf[5] = (_Float16)u1.y;
        bf[6] = (_Float16)u1.z; bf[7] = (_Float16)u1.w;
        f16x8 af = Wf[(cg * 8 + kk) * 64 + lane];
        acc = __builtin_amdgcn_mfma_f32_16x16x32_f16(af, bf, acc, 0, 0, 0);
    }

    // ---- Phase A: lane owns run r = 4cg + l4 ----
    {
        const int r = 4 * cg + l4;
        float4 bb = *(const float4*)(bp + 4 * r);
        float bias[4] = {bb.x, bb.y, bb.z, bb.w};
        float cc[4], ssn[4];
        #pragma unroll
        for (int w = 0; w < 4; ++w) {
            float pre = acc[w] + bias[w];
            float e   = __expf(2.f * pre);
            float th  = __fdividef(e - 1.f, e + 1.f);   // tanh(pre)
            float hh  = th * (0.5f * PI_F);             // theta/2
            __sincosf(hh, &ssn[w], &cc[w]);
        }
        float* slot = tab + (r * 16 + l15) * 9;
        slot[0] = cc[0] * cc[1];  slot[1] = cc[0] * ssn[1];
        slot[2] = ssn[0] * cc[1]; slot[3] = ssn[0] * ssn[1];
        slot[4] = cc[2] * cc[3];  slot[5] = cc[2] * ssn[3];
        slot[6] = ssn[2] * cc[3]; slot[7] = ssn[2] * ssn[3];
    }
    // tab slots for this wave's runs are written/read by the same wave only
    // (wave-synchronous LDS ordering) -> no barrier.

    // ---- Phase B: 4 runs, each one mfma (A=[U_hi|U_lo], B=[se;se]) ----
    const float sg0 = (l4 < 2) ? 1.f : -1.f;        // sign of state bit3
    const float sg1 = ((l4 & 1) == 0) ? 1.f : -1.f; // sign of state bit2
    const int   h8  = (l4 & 1) * 2;                 // a01 base for se half
    const f16x8* UA = (const f16x8*)(ws + 32768);

    #pragma unroll
    for (int rr = 0; rr < 4; ++rr) {
        const int r = 4 * cg + rr;
        const float* t = tab + (r * 16 + l15) * 9;
        float a01a = t[h8], a01b = t[h8 + 1];
        float b0 = t[4], b1 = t[5], b2 = t[6], b3 = t[7];
        f16x8 se;
        se[0] = (_Float16)(a01a * b0); se[1] = (_Float16)(a01a * b1);
        se[2] = (_Float16)(a01a * b2); se[3] = (_Float16)(a01a * b3);
        se[4] = (_Float16)(a01b * b0); se[5] = (_Float16)(a01b * b1);
        se[6] = (_Float16)(a01b * b2); se[7] = (_Float16)(a01b * b3);

        f16x8 ua = UA[r * 64 + lane];
        f32x4 zero = {};
        f32x4 o = __builtin_amdgcn_mfma_f32_16x16x32_f16(ua, se, zero, 0, 0, 0);

        // lane holds states 4*l4+j of sample l15
        float p0 = o[0] * o[0], p1 = o[1] * o[1];
        float p2 = o[2] * o[2], p3 = o[3] * o[3];
        float S  = (p0 + p1) + (p2 + p3);
        float z0 = sg0 * S;
        float z1 = sg1 * S;
        float z2 = (p0 + p1) - (p2 + p3);
        float z3 = (p0 - p1) + (p2 - p3);
        z0 += __shfl_xor(z0, 16); z0 += __shfl_xor(z0, 32);
        z1 += __shfl_xor(z1, 16); z1 += __shfl_xor(z1, 32);
        z2 += __shfl_xor(z2, 16); z2 += __shfl_xor(z2, 32);
        z3 += __shfl_xor(z3, 16); z3 += __shfl_xor(z3, 32);

        if (l4 == rr) {
            float4 ov;
            ov.x = (z0 + 1.f) * PI_F;
            ov.y = (z1 + 1.f) * PI_F;
            ov.z = (z2 + 1.f) * PI_F;
            ov.w = (z3 + 1.f) * PI_F;
            *(float4*)(out + (s0 + l15) * 64 + 4 * r) = ov;
        }
    }
}

extern "C" void kernel_launch(void* const* d_in, const int* in_sizes, int n_in,
                              void* d_out, int out_size, void* d_ws, size_t ws_size,
                              hipStream_t stream) {
    const float* fused = (const float*)d_in[0];   // (65536, 256)
    const float* Wp    = (const float*)d_in[1];   // (64, 256)
    const float* bp    = (const float*)d_in[2];   // (64,)
    const float* vw    = (const float*)d_in[3];   // (16, 4, 4)
    float* out = (float*)d_out;                   // (65536, 64)
    char*  ws  = (char*)d_ws;                     // 64 KB used

    prep_kernel<<<2, 256, 0, stream>>>(vw, Wp, ws);

    const int B = 65536;
    vqc_main_kernel<<<B / 16, 256, 0, stream>>>(fused, ws, bp, out);
}

// Round 7
// 31.763 us; speedup vs baseline: 1.6460x; 1.6460x over previous
//
#include <hip/hip_runtime.h>
#include <math.h>

// ---------------------------------------------------------------------------
// RISVQCLayer: angles = tanh(fused @ W^T + b) * pi  -> 4-qubit VQC -> (z+1)*pi
// B=65536, HID=256, R=16 runs (64 outputs/sample), fp32 in/out.
//
// R6: no-redundancy run-split. Block = 256 thr / 4 waves, 32-sample tile.
//  - fused staged ONCE per block (fp32->fp16, XOR-swizzled, coalesced), both
//    sample groups' B-fragments read from LDS by every wave.
//  - wave cg owns runs 4cg..4cg+3; lane (l15,l4) owns run 4cg+l4.
//  - Wf/UA/bias prefetched to registers BEFORE the staging barrier (MLP).
//  - U-apply = one mfma_16x16x32_f16 per (run, sg): A=[U_hi|U_lo] split fp16
//    (R4-verified), B=[se;se]. Z via signed sums + shfl_xor(16,32).
//  - tab = fp16 factor table (8 KB), wave-private -> single barrier total.
//  - LDS 24.5 KB -> 6 blocks/CU; launch_bounds(256,3) -> no VGPR strangle.
// d_ws: [0,32K) Wf fp16 frags; [32K,48K) UA fp16 frags; [48K,64K) U fp32 tmp.
// ---------------------------------------------------------------------------

#define PI_F 3.14159265358979323846f

typedef _Float16 f16x4 __attribute__((ext_vector_type(4)));
typedef _Float16 f16x8 __attribute__((ext_vector_type(8)));
typedef float    f32x4 __attribute__((ext_vector_type(4)));

__device__ __forceinline__ void ry_gate(float st[16], float c, float s, int w) {
    const int m = 1 << (3 - w);
    #pragma unroll
    for (int i = 0; i < 16; ++i) {
        if (i & m) continue;
        float a = st[i];
        float b = st[i | m];
        st[i]     = c * a - s * b;
        st[i | m] = s * a + c * b;
    }
}

__device__ __forceinline__ void cnot_gate(float st[16], int cw, int tw) {
    const int cm = 1 << (3 - cw);
    const int tm = 1 << (3 - tw);
    #pragma unroll
    for (int i = 0; i < 16; ++i) {
        if ((i & cm) && !(i & tm)) {
            float tmp = st[i];
            st[i] = st[i | tm];
            st[i | tm] = tmp;
        }
    }
}

// prep: block0 -> U matrices then fp16 hi/lo A-fragments; block1 -> W frags.
// (layouts verified R3/R4/R5)
__global__ void prep_kernel(const float* __restrict__ vw,
                            const float* __restrict__ W,
                            char* __restrict__ ws) {
    const int tid = threadIdx.x;   // 256
    if (blockIdx.x == 0) {
        float* Ut = (float*)(ws + 49152);          // fp32 U[r][i][j]
        {   // phase 1: thread (r, j) computes column j of U_r
            const int r = tid >> 4, j = tid & 15;
            const float* wr = vw + r * 16;
            float cs[16], sn[16];
            #pragma unroll
            for (int i = 0; i < 16; ++i) {
                float h = wr[i] * 0.5f;
                cs[i] = __cosf(h);
                sn[i] = __sinf(h);
            }
            float st[16];
            #pragma unroll
            for (int i = 0; i < 16; ++i) st[i] = 0.f;
            st[j] = 1.f;
            #pragma unroll
            for (int w = 0; w < 4; ++w) ry_gate(st, cs[w], sn[w], w);
            cnot_gate(st, 0, 1);
            cnot_gate(st, 2, 3);
            #pragma unroll
            for (int w = 0; w < 4; ++w) ry_gate(st, cs[4 + w], sn[4 + w], w);
            cnot_gate(st, 1, 2);
            cnot_gate(st, 3, 0);
            #pragma unroll
            for (int w = 0; w < 4; ++w) ry_gate(st, cs[8 + w], sn[8 + w], w);
            cnot_gate(st, 0, 1);
            cnot_gate(st, 1, 2);
            cnot_gate(st, 2, 3);
            cnot_gate(st, 3, 0);
            #pragma unroll
            for (int w = 0; w < 4; ++w) ry_gate(st, cs[12 + w], sn[12 + w], w);
            #pragma unroll
            for (int i = 0; i < 16; ++i) Ut[r * 256 + i * 16 + j] = st[i];
        }
        __syncthreads();
        {   // phase 2: UA[r][lane]: k<16 -> hi(U[l15][k]), k>=16 -> lo(...)
            _Float16* UA = (_Float16*)(ws + 32768);
            #pragma unroll
            for (int t = 0; t < 4; ++t) {
                int f = t * 256 + tid;             // 0..1023
                int r = f >> 6, lane = f & 63;
                int l15 = lane & 15, l4 = lane >> 4;
                const float* urow = Ut + r * 256 + l15 * 16;
                f16x8 h;
                #pragma unroll
                for (int e = 0; e < 8; ++e) {
                    int kl = 8 * l4 + e;
                    if (kl < 16) {
                        h[e] = (_Float16)urow[kl];
                    } else {
                        float u = urow[kl - 16];
                        _Float16 hi = (_Float16)u;
                        h[e] = (_Float16)(u - (float)hi);
                    }
                }
                *(f16x8*)(UA + f * 8) = h;
            }
        }
    } else {
        // W fragments: row=cg*16+l15, k=(kk*4+l4)*8+e
        _Float16* Wh = (_Float16*)ws;
        #pragma unroll
        for (int t = 0; t < 8; ++t) {
            int f  = tid * 8 + t;            // fragment id 0..2047
            int cg = f >> 9;
            int kk = (f >> 6) & 7;
            int l  = f & 63;
            int row = cg * 16 + (l & 15);
            int k0  = (kk * 4 + (l >> 4)) * 8;
            const float* src = W + row * 256 + k0;
            f16x8 h;
            #pragma unroll
            for (int e = 0; e < 8; ++e) h[e] = (_Float16)src[e];
            *(f16x8*)(Wh + f * 8) = h;
        }
    }
}

__global__ __launch_bounds__(256, 3) void vqc_main_kernel(
        const float* __restrict__ fused,   // (65536, 256)
        const char* __restrict__ ws,       // Wf + UA fragments
        const float* __restrict__ bp,      // (64,)
        float* __restrict__ out) {         // (65536, 64)
    // [0,16K): fused tile fp16 swizzled (32 rows x 512B); [16K,24.5K): tab
    __shared__ __align__(16) char smem[16384 + 16 * 32 * 16];

    const int tid  = threadIdx.x;
    const int lane = tid & 63;
    const int cg   = tid >> 6;             // wave id = run group
    const int l15  = lane & 15;
    const int l4   = lane >> 4;
    const size_t b0 = (size_t)blockIdx.x * 32;

    // ---- register prefetch (independent of LDS staging) ----
    const f16x8* Wf = (const f16x8*)ws;
    f16x8 af[8];
    #pragma unroll
    for (int kk = 0; kk < 8; ++kk) af[kk] = Wf[(cg * 8 + kk) * 64 + lane];

    const f16x8* UA = (const f16x8*)(ws + 32768);
    f16x8 ua[4];
    #pragma unroll
    for (int rr = 0; rr < 4; ++rr) ua[rr] = UA[(4 * cg + rr) * 64 + lane];

    float4 bb = *(const float4*)(bp + 4 * (4 * cg + l4));   // lane's run bias

    // ---- stage fused 32x256 fp32->fp16, XOR-swizzled, coalesced ----
    {
        const float4* s4 = (const float4*)(fused + b0 * 256);
        #pragma unroll
        for (int it = 0; it < 8; ++it) {
            int q = tid + it * 256;        // float4 index, 2048 total
            float4 v = s4[q];
            int row = q >> 6;
            int c4  = (q & 63) << 2;
            int sl  = (c4 >> 3) ^ (row & 7);
            int byteoff = row * 512 + (sl << 4) + ((c4 & 7) << 1);
            f16x4 h = { (_Float16)v.x, (_Float16)v.y, (_Float16)v.z, (_Float16)v.w };
            *(f16x4*)(smem + byteoff) = h;
        }
    }
    __syncthreads();

    // ---- MFMA: acc[sg][j] = pre[sample sg*16+l15][angle 16cg+4l4+j] ----
    f32x4 acc[2] = {};
    #pragma unroll
    for (int kk = 0; kk < 8; ++kk) {
        int slot = kk * 4 + l4;
        #pragma unroll
        for (int sg = 0; sg < 2; ++sg) {
            int frow = sg * 16 + l15;
            f16x8 bf = *(const f16x8*)(smem + frow * 512 + ((slot ^ (frow & 7)) << 4));
            acc[sg] = __builtin_amdgcn_mfma_f32_16x16x32_f16(af[kk], bf, acc[sg], 0, 0, 0);
        }
    }

    // ---- Phase A: lane owns run r = 4cg+l4; fp16 factor table (wave-private)
    _Float16* tab = (_Float16*)(smem + 16384);   // [16 runs][32 samples] x8
    const int r_own = 4 * cg + l4;
    #pragma unroll
    for (int sg = 0; sg < 2; ++sg) {
        float bias[4] = {bb.x, bb.y, bb.z, bb.w};
        float cc[4], ssn[4];
        #pragma unroll
        for (int w = 0; w < 4; ++w) {
            float pre = acc[sg][w] + bias[w];
            float e   = __expf(2.f * pre);
            float th  = __fdividef(e - 1.f, e + 1.f);   // tanh(pre)
            float hh  = th * (0.5f * PI_F);             // theta/2
            __sincosf(hh, &ssn[w], &cc[w]);
        }
        f16x8 t;
        t[0] = (_Float16)(cc[0] * cc[1]);  t[1] = (_Float16)(cc[0] * ssn[1]);
        t[2] = (_Float16)(ssn[0] * cc[1]); t[3] = (_Float16)(ssn[0] * ssn[1]);
        t[4] = (_Float16)(cc[2] * cc[3]);  t[5] = (_Float16)(cc[2] * ssn[3]);
        t[6] = (_Float16)(ssn[2] * cc[3]); t[7] = (_Float16)(ssn[2] * ssn[3]);
        *(f16x8*)(tab + (r_own * 32 + sg * 16 + l15) * 8) = t;
    }
    // tab region [4cg..4cg+3] written & read by wave cg only -> no barrier.

    // ---- Phase B: per (run, sg): one mfma, signed sums, shfl reduce ----
    const float g0 = (l4 < 2) ? 1.f : -1.f;        // sign of state bit3
    const float g1 = ((l4 & 1) == 0) ? 1.f : -1.f; // sign of state bit2
    const int   h8 = (l4 & 1) * 2;                 // a01 base for se half

    #pragma unroll
    for (int rr = 0; rr < 4; ++rr) {
        const int r = 4 * cg + rr;
        #pragma unroll
        for (int sg = 0; sg < 2; ++sg) {
            f16x8 t = *(const f16x8*)(tab + (r * 32 + sg * 16 + l15) * 8);
            _Float16 a01a = t[h8], a01b = t[h8 + 1];
            f16x8 se;
            se[0] = a01a * t[4]; se[1] = a01a * t[5];
            se[2] = a01a * t[6]; se[3] = a01a * t[7];
            se[4] = a01b * t[4]; se[5] = a01b * t[5];
            se[6] = a01b * t[6]; se[7] = a01b * t[7];

            f32x4 zero = {};
            f32x4 o = __builtin_amdgcn_mfma_f32_16x16x32_f16(ua[rr], se, zero, 0, 0, 0);

            // lane holds states 4*l4+j of sample sg*16+l15
            float p0 = o[0] * o[0], p1 = o[1] * o[1];
            float p2 = o[2] * o[2], p3 = o[3] * o[3];
            float S  = (p0 + p1) + (p2 + p3);
            float z0 = g0 * S;
            float z1 = g1 * S;
            float z2 = (p0 + p1) - (p2 + p3);
            float z3 = (p0 - p1) + (p2 - p3);
            z0 += __shfl_xor(z0, 16); z0 += __shfl_xor(z0, 32);
            z1 += __shfl_xor(z1, 16); z1 += __shfl_xor(z1, 32);
            z2 += __shfl_xor(z2, 16); z2 += __shfl_xor(z2, 32);
            z3 += __shfl_xor(z3, 16); z3 += __shfl_xor(z3, 32);

            if (l4 == rr) {
                float4 ov;
                ov.x = (z0 + 1.f) * PI_F;
                ov.y = (z1 + 1.f) * PI_F;
                ov.z = (z2 + 1.f) * PI_F;
                ov.w = (z3 + 1.f) * PI_F;
                *(float4*)(out + (b0 + sg * 16 + l15) * 64 + 4 * r) = ov;
            }
        }
    }
}

extern "C" void kernel_launch(void* const* d_in, const int* in_sizes, int n_in,
                              void* d_out, int out_size, void* d_ws, size_t ws_size,
                              hipStream_t stream) {
    const float* fused = (const float*)d_in[0];   // (65536, 256)
    const float* Wp    = (const float*)d_in[1];   // (64, 256)
    const float* bp    = (const float*)d_in[2];   // (64,)
    const float* vw    = (const float*)d_in[3];   // (16, 4, 4)
    float* out = (float*)d_out;                   // (65536, 64)
    char*  ws  = (char*)d_ws;                     // 64 KB used

    prep_kernel<<<2, 256, 0, stream>>>(vw, Wp, ws);

    const int B = 65536;
    vqc_main_kernel<<<B / 32, 256, 0, stream>>>(fused, ws, bp, out);
}

// Round 8
// 26.628 us; speedup vs baseline: 1.9633x; 1.1928x over previous
//
#include <hip/hip_runtime.h>
#include <math.h>

// ---------------------------------------------------------------------------
// RISVQCLayer: angles = tanh(fused @ W^T + b) * pi  -> 4-qubit VQC -> (z+1)*pi
// B=65536, HID=256, R=16 runs (64 outputs/sample), fp32 in/out.
//
// R7 = R6 with Phase B moved to mfma_f32_32x32x16_f16:
//  - A-operand (prepacked UA32): rows 0-15 = U_hi, rows 16-31 = U_lo (split
//    fp16 -> exact U), K=16 = se (no [se;se] duplication).
//  - One MFMA per run covers all 32 samples; hi/lo parts land in the SAME
//    lane (C/D map: col=lane&31, row=(reg&3)+8(reg>>2)+4(lane>>5)) -> 8 adds.
//  - Lane (s,h) holds states {4h+0..3, 8+4h+0..3} -> single shfl_xor(32)
//    reduction; z1 sign is lane-constant.
//  - Phase B per wave: 4 MFMA + 4 tab reads + 16 shuffles (was 8/8/64).
// GEMM phase / Phase A / staging / tab layout identical to R6 (verified).
// d_ws: [0,32K) Wf fp16 frags; [32K,48K) UA32 fp16 frags; [48K,64K) U fp32.
// ---------------------------------------------------------------------------

#define PI_F 3.14159265358979323846f

typedef _Float16 f16x4 __attribute__((ext_vector_type(4)));
typedef _Float16 f16x8 __attribute__((ext_vector_type(8)));
typedef float    f32x4 __attribute__((ext_vector_type(4)));
typedef float    f32x16 __attribute__((ext_vector_type(16)));

__device__ __forceinline__ void ry_gate(float st[16], float c, float s, int w) {
    const int m = 1 << (3 - w);
    #pragma unroll
    for (int i = 0; i < 16; ++i) {
        if (i & m) continue;
        float a = st[i];
        float b = st[i | m];
        st[i]     = c * a - s * b;
        st[i | m] = s * a + c * b;
    }
}

__device__ __forceinline__ void cnot_gate(float st[16], int cw, int tw) {
    const int cm = 1 << (3 - cw);
    const int tm = 1 << (3 - tw);
    #pragma unroll
    for (int i = 0; i < 16; ++i) {
        if ((i & cm) && !(i & tm)) {
            float tmp = st[i];
            st[i] = st[i | tm];
            st[i | tm] = tmp;
        }
    }
}

// prep: block0 -> U matrices then UA32 fragments; block1 -> W frags.
__global__ void prep_kernel(const float* __restrict__ vw,
                            const float* __restrict__ W,
                            char* __restrict__ ws) {
    const int tid = threadIdx.x;   // 256
    if (blockIdx.x == 0) {
        float* Ut = (float*)(ws + 49152);          // fp32 U[r][i][j]
        {   // phase 1: thread (r, j) computes column j of U_r
            const int r = tid >> 4, j = tid & 15;
            const float* wr = vw + r * 16;
            float cs[16], sn[16];
            #pragma unroll
            for (int i = 0; i < 16; ++i) {
                float h = wr[i] * 0.5f;
                cs[i] = __cosf(h);
                sn[i] = __sinf(h);
            }
            float st[16];
            #pragma unroll
            for (int i = 0; i < 16; ++i) st[i] = 0.f;
            st[j] = 1.f;
            #pragma unroll
            for (int w = 0; w < 4; ++w) ry_gate(st, cs[w], sn[w], w);
            cnot_gate(st, 0, 1);
            cnot_gate(st, 2, 3);
            #pragma unroll
            for (int w = 0; w < 4; ++w) ry_gate(st, cs[4 + w], sn[4 + w], w);
            cnot_gate(st, 1, 2);
            cnot_gate(st, 3, 0);
            #pragma unroll
            for (int w = 0; w < 4; ++w) ry_gate(st, cs[8 + w], sn[8 + w], w);
            cnot_gate(st, 0, 1);
            cnot_gate(st, 1, 2);
            cnot_gate(st, 2, 3);
            cnot_gate(st, 3, 0);
            #pragma unroll
            for (int w = 0; w < 4; ++w) ry_gate(st, cs[12 + w], sn[12 + w], w);
            #pragma unroll
            for (int i = 0; i < 16; ++i) Ut[r * 256 + i * 16 + j] = st[i];
        }
        __syncthreads();
        {   // phase 2: UA32[r][lane]: i=lane&31, h=lane>>5, k=8h+e (K=16):
            //          i<16 -> hi(U[i][k]); i>=16 -> lo(U[i-16][k])
            _Float16* UA = (_Float16*)(ws + 32768);
            #pragma unroll
            for (int t = 0; t < 4; ++t) {
                int f = t * 256 + tid;             // 0..1023
                int r = f >> 6, lane = f & 63;
                int i = lane & 31, hh = lane >> 5;
                const float* urow = Ut + r * 256 + (i & 15) * 16;
                f16x8 h;
                #pragma unroll
                for (int e = 0; e < 8; ++e) {
                    float u = urow[8 * hh + e];
                    if (i < 16) {
                        h[e] = (_Float16)u;
                    } else {
                        _Float16 hi = (_Float16)u;
                        h[e] = (_Float16)(u - (float)hi);
                    }
                }
                *(f16x8*)(UA + f * 8) = h;
            }
        }
    } else {
        // W fragments: row=cg*16+l15, k=(kk*4+l4)*8+e
        _Float16* Wh = (_Float16*)ws;
        #pragma unroll
        for (int t = 0; t < 8; ++t) {
            int f  = tid * 8 + t;            // fragment id 0..2047
            int cg = f >> 9;
            int kk = (f >> 6) & 7;
            int l  = f & 63;
            int row = cg * 16 + (l & 15);
            int k0  = (kk * 4 + (l >> 4)) * 8;
            const float* src = W + row * 256 + k0;
            f16x8 h;
            #pragma unroll
            for (int e = 0; e < 8; ++e) h[e] = (_Float16)src[e];
            *(f16x8*)(Wh + f * 8) = h;
        }
    }
}

__global__ __launch_bounds__(256, 3) void vqc_main_kernel(
        const float* __restrict__ fused,   // (65536, 256)
        const char* __restrict__ ws,       // Wf + UA32 fragments
        const float* __restrict__ bp,      // (64,)
        float* __restrict__ out) {         // (65536, 64)
    // [0,16K): fused tile fp16 swizzled (32 rows x 512B); [16K,24.5K): tab
    __shared__ __align__(16) char smem[16384 + 16 * 32 * 16];

    const int tid  = threadIdx.x;
    const int lane = tid & 63;
    const int cg   = tid >> 6;             // wave id = run group
    const int l15  = lane & 15;
    const int l4   = lane >> 4;
    const size_t b0 = (size_t)blockIdx.x * 32;

    // ---- register prefetch (independent of LDS staging) ----
    const f16x8* Wf = (const f16x8*)ws;
    f16x8 af[8];
    #pragma unroll
    for (int kk = 0; kk < 8; ++kk) af[kk] = Wf[(cg * 8 + kk) * 64 + lane];

    const f16x8* UA = (const f16x8*)(ws + 32768);
    f16x8 ua[4];
    #pragma unroll
    for (int rr = 0; rr < 4; ++rr) ua[rr] = UA[(4 * cg + rr) * 64 + lane];

    float4 bb = *(const float4*)(bp + 4 * (4 * cg + l4));   // lane's run bias

    // ---- stage fused 32x256 fp32->fp16, XOR-swizzled, coalesced ----
    {
        const float4* s4 = (const float4*)(fused + b0 * 256);
        #pragma unroll
        for (int it = 0; it < 8; ++it) {
            int q = tid + it * 256;        // float4 index, 2048 total
            float4 v = s4[q];
            int row = q >> 6;
            int c4  = (q & 63) << 2;
            int sl  = (c4 >> 3) ^ (row & 7);
            int byteoff = row * 512 + (sl << 4) + ((c4 & 7) << 1);
            f16x4 h = { (_Float16)v.x, (_Float16)v.y, (_Float16)v.z, (_Float16)v.w };
            *(f16x4*)(smem + byteoff) = h;
        }
    }
    __syncthreads();

    // ---- MFMA: acc[sg][j] = pre[sample sg*16+l15][angle 16cg+4l4+j] ----
    f32x4 acc[2] = {};
    #pragma unroll
    for (int kk = 0; kk < 8; ++kk) {
        int slot = kk * 4 + l4;
        #pragma unroll
        for (int sg = 0; sg < 2; ++sg) {
            int frow = sg * 16 + l15;
            f16x8 bf = *(const f16x8*)(smem + frow * 512 + ((slot ^ (frow & 7)) << 4));
            acc[sg] = __builtin_amdgcn_mfma_f32_16x16x32_f16(af[kk], bf, acc[sg], 0, 0, 0);
        }
    }

    // ---- Phase A: lane owns run r = 4cg+l4; fp16 factor table (wave-private)
    _Float16* tab = (_Float16*)(smem + 16384);   // [16 runs][32 samples] x8
    const int r_own = 4 * cg + l4;
    #pragma unroll
    for (int sg = 0; sg < 2; ++sg) {
        float bias[4] = {bb.x, bb.y, bb.z, bb.w};
        float cc[4], ssn[4];
        #pragma unroll
        for (int w = 0; w < 4; ++w) {
            float pre = acc[sg][w] + bias[w];
            float e   = __expf(2.f * pre);
            float th  = __fdividef(e - 1.f, e + 1.f);   // tanh(pre)
            float hh  = th * (0.5f * PI_F);             // theta/2
            __sincosf(hh, &ssn[w], &cc[w]);
        }
        f16x8 t;
        t[0] = (_Float16)(cc[0] * cc[1]);  t[1] = (_Float16)(cc[0] * ssn[1]);
        t[2] = (_Float16)(ssn[0] * cc[1]); t[3] = (_Float16)(ssn[0] * ssn[1]);
        t[4] = (_Float16)(cc[2] * cc[3]);  t[5] = (_Float16)(cc[2] * ssn[3]);
        t[6] = (_Float16)(ssn[2] * cc[3]); t[7] = (_Float16)(ssn[2] * ssn[3]);
        *(f16x8*)(tab + (r_own * 32 + sg * 16 + l15) * 8) = t;
    }
    // tab region [4cg..4cg+3] written & read by wave cg only -> no barrier.

    // ---- Phase B: per run ONE mfma_32x32x16 over all 32 samples ----
    const int   s  = lane & 31;            // sample within tile
    const int   hh = lane >> 5;            // state half (bit2 of state)
    const float g1 = hh ? -1.f : 1.f;

    #pragma unroll
    for (int rr = 0; rr < 4; ++rr) {
        const int r = 4 * cg + rr;
        f16x8 t = *(const f16x8*)(tab + (r * 32 + s) * 8);
        _Float16 a0 = t[2 * hh], a1 = t[2 * hh + 1];   // a01[2h], a01[2h+1]
        f16x8 se;
        se[0] = a0 * t[4]; se[1] = a0 * t[5];
        se[2] = a0 * t[6]; se[3] = a0 * t[7];
        se[4] = a1 * t[4]; se[5] = a1 * t[5];
        se[6] = a1 * t[6]; se[7] = a1 * t[7];

        f32x16 zero = {};
        f32x16 o = __builtin_amdgcn_mfma_f32_32x32x16_f16(ua[rr], se, zero, 0, 0, 0);

        // combine hi/lo: full state s' = (j&3)+8*(j>>2)+4*hh, j=0..7
        float p[8];
        #pragma unroll
        for (int j = 0; j < 8; ++j) {
            float of = o[j] + o[j + 8];
            p[j] = of * of;
        }
        float a = p[0] + p[1], b = p[2] + p[3];
        float c = p[4] + p[5], d = p[6] + p[7];
        float ab = a + b, cd = c + d;
        float z0 = ab - cd;                 // bit3 sign
        float z1 = g1 * (ab + cd);          // bit2 = hh
        float z2 = (a - b) + (c - d);       // bit1
        float z3 = (p[0] - p[1] + p[2] - p[3]) + (p[4] - p[5] + p[6] - p[7]);

        z0 += __shfl_xor(z0, 32);
        z1 += __shfl_xor(z1, 32);
        z2 += __shfl_xor(z2, 32);
        z3 += __shfl_xor(z3, 32);

        if (hh == 0) {
            float4 ov;
            ov.x = (z0 + 1.f) * PI_F;
            ov.y = (z1 + 1.f) * PI_F;
            ov.z = (z2 + 1.f) * PI_F;
            ov.w = (z3 + 1.f) * PI_F;
            *(float4*)(out + (b0 + s) * 64 + 4 * r) = ov;
        }
    }
}

extern "C" void kernel_launch(void* const* d_in, const int* in_sizes, int n_in,
                              void* d_out, int out_size, void* d_ws, size_t ws_size,
                              hipStream_t stream) {
    const float* fused = (const float*)d_in[0];   // (65536, 256)
    const float* Wp    = (const float*)d_in[1];   // (64, 256)
    const float* bp    = (const float*)d_in[2];   // (64,)
    const float* vw    = (const float*)d_in[3];   // (16, 4, 4)
    float* out = (float*)d_out;                   // (65536, 64)
    char*  ws  = (char*)d_ws;                     // 64 KB used

    prep_kernel<<<2, 256, 0, stream>>>(vw, Wp, ws);

    const int B = 65536;
    vqc_main_kernel<<<B / 32, 256, 0, stream>>>(fused, ws, bp, out);
}